// Round 12
// baseline (137.090 us; speedup 1.0000x reference)
//
#include <hip/hip_runtime.h>
#include <math.h>

#define HW 16384
#define C_DIM 256
#define V_DIM 6
#define PT 64
#define BK 32
#define KROW 40            // ushorts per pixel-row (80 B): b128 ops at bank floor
#define KT (PT * KROW)     // ushorts per K-tile in LDS

typedef short bf16x8 __attribute__((ext_vector_type(8)));
typedef float f32x4 __attribute__((ext_vector_type(4)));

// fp32 -> bf16 hi/lo split (truncation). |x - (hi+lo)| <= 2^-16 |x|.
__device__ __forceinline__ void split2(float x, unsigned short& h,
                                       unsigned short& l) {
    unsigned u = __float_as_uint(x);
    h = (unsigned short)(u >> 16);
    float xl = x - __uint_as_float(u & 0xFFFF0000u);
    l = (unsigned short)(__float_as_uint(xl) >> 16);
}

// ---------------------------------------------------------------------------
// K1: M = Wq^T @ Wk, stored as bf16 hi/lo.
// ---------------------------------------------------------------------------
__global__ void compute_M_kernel(const float* __restrict__ Wq,
                                 const float* __restrict__ Wk,
                                 unsigned short* __restrict__ Mh,
                                 unsigned short* __restrict__ Ml) {
    const int i = blockIdx.x;
    const int j = threadIdx.x;
    float a0 = 0.f, a1 = 0.f, a2 = 0.f, a3 = 0.f;
    #pragma unroll 4
    for (int o = 0; o < C_DIM; o += 4) {
        a0 = fmaf(Wq[(o + 0) * C_DIM + i], Wk[(o + 0) * C_DIM + j], a0);
        a1 = fmaf(Wq[(o + 1) * C_DIM + i], Wk[(o + 1) * C_DIM + j], a1);
        a2 = fmaf(Wq[(o + 2) * C_DIM + i], Wk[(o + 2) * C_DIM + j], a2);
        a3 = fmaf(Wq[(o + 3) * C_DIM + i], Wk[(o + 3) * C_DIM + j], a3);
    }
    float acc = (a0 + a1) + (a2 + a3);
    unsigned short h, l;
    split2(acc, h, l);
    Mh[i * C_DIM + j] = h;
    Ml[i * C_DIM + j] = l;
}

// ---------------------------------------------------------------------------
// K2 v12: FULLY-RESIDENT operands; the main loop touches only LDS + MFMA.
// Every structure tried in r2..r11 (LDS-staged A, global A, 0-3-deep
// prefetch, 0/1/2 barriers per ks) measured 93-108 us -- the shared cost is
// per-ks operand staging on the critical path. Here:
//   * K: 32 coalesced loads/thread -> split -> 8-tile LDS image (80 KB).
//   * A: this wave's 32 i-rows x K=256 of M hi/lo loaded ONCE into 128
//     VGPRs (32 b128 L2 loads, issued together; M L2 traffic drops 8x).
//   * ONE barrier, then 8 x {8 ds_read_b128 + 24 MFMA}: no global ops, no
//     barriers, nothing for a waitcnt to drain.
// 512 thr = 8 waves; wave w owns i-rows [32w, 32w+32); acc[2][4] = 32 AGPR.
// ---------------------------------------------------------------------------
__global__ __launch_bounds__(512, 2) void score_kernel(
        const float* __restrict__ q, const float* __restrict__ k,
        const unsigned short* __restrict__ Mh,
        const unsigned short* __restrict__ Ml,
        float* __restrict__ score) {
    const int tid  = threadIdx.x;
    const int lane = tid & 63;          // staging pixel
    const int w    = tid >> 6;          // wave 0..7; staging ch-group (4 ch)
    const int pt   = blockIdx.x & 255;
    const int v    = blockIdx.x >> 8;
    const int gp0  = pt * PT;
    const int l15  = lane & 15;
    const int l4   = lane >> 4;

    __shared__ __align__(16) unsigned short Kh_s[8 * KT];   // 40 KB
    __shared__ __align__(16) unsigned short Kl_s[8 * KT];   // 40 KB

    const float* kv = k + (size_t)v * C_DIM * HW + gp0;
    const float* qv = q + (size_t)v * C_DIM * HW + gp0;
    const int ibase = w * 32;

    // ---- stage ALL of k: 32 coalesced loads -> split -> 8 LDS tiles ----
    {
        float kx[8][4];
        #pragma unroll
        for (int t = 0; t < 8; ++t) {
            const float* kp = kv + (size_t)(t * BK + w * 4) * HW + lane;
            #pragma unroll
            for (int e = 0; e < 4; ++e) kx[t][e] = kp[(size_t)e * HW];
        }
        #pragma unroll
        for (int t = 0; t < 8; ++t) {
            unsigned short h[4], l[4];
            #pragma unroll
            for (int e = 0; e < 4; ++e) split2(kx[t][e], h[e], l[e]);
            uint2 H, L;
            H.x = (unsigned)h[0] | ((unsigned)h[1] << 16);
            H.y = (unsigned)h[2] | ((unsigned)h[3] << 16);
            L.x = (unsigned)l[0] | ((unsigned)l[1] << 16);
            L.y = (unsigned)l[2] | ((unsigned)l[3] << 16);
            *(uint2*)&Kh_s[t * KT + lane * KROW + w * 4] = H;
            *(uint2*)&Kl_s[t * KT + lane * KROW + w * 4] = L;
        }
    }

    // ---- load this wave's FULL A panel (32 rows x K=256, hi/lo): 128 VGPR ----
    bf16x8 Ah[8][2], Al[8][2];
    #pragma unroll
    for (int ks = 0; ks < 8; ++ks)
        #pragma unroll
        for (int it = 0; it < 2; ++it) {
            int row = ibase + it * 16 + l15;
            Ah[ks][it] = *(const bf16x8*)(Mh + (size_t)row * C_DIM +
                                          ks * BK + l4 * 8);
            Al[ks][it] = *(const bf16x8*)(Ml + (size_t)row * C_DIM +
                                          ks * BK + l4 * 8);
        }

    __syncthreads();   // the ONLY barrier before the epilogue

    f32x4 acc[2][4];
    #pragma unroll
    for (int a = 0; a < 2; ++a)
        #pragma unroll
        for (int b = 0; b < 4; ++b)
            acc[a][b] = (f32x4){0.f, 0.f, 0.f, 0.f};

    // ---- main loop: LDS reads + MFMA only ----
    #pragma unroll
    for (int ks = 0; ks < 8; ++ks) {
        bf16x8 Bh[4];
        #pragma unroll
        for (int jt = 0; jt < 4; ++jt) {
            int bp = jt * 16 + l15;
            Bh[jt] = *(const bf16x8*)&Kh_s[ks * KT + bp * KROW + l4 * 8];
        }
        #pragma unroll
        for (int it = 0; it < 2; ++it)
            #pragma unroll
            for (int jt = 0; jt < 4; ++jt)
                acc[it][jt] = __builtin_amdgcn_mfma_f32_16x16x32_bf16(
                                  Ah[ks][it], Bh[jt], acc[it][jt], 0, 0, 0);
        #pragma unroll
        for (int it = 0; it < 2; ++it)
            #pragma unroll
            for (int jt = 0; jt < 4; ++jt)
                acc[it][jt] = __builtin_amdgcn_mfma_f32_16x16x32_bf16(
                                  Al[ks][it], Bh[jt], acc[it][jt], 0, 0, 0);
        bf16x8 Bl[4];
        #pragma unroll
        for (int jt = 0; jt < 4; ++jt) {
            int bp = jt * 16 + l15;
            Bl[jt] = *(const bf16x8*)&Kl_s[ks * KT + bp * KROW + l4 * 8];
        }
        #pragma unroll
        for (int it = 0; it < 2; ++it)
            #pragma unroll
            for (int jt = 0; jt < 4; ++jt)
                acc[it][jt] = __builtin_amdgcn_mfma_f32_16x16x32_bf16(
                                  Ah[ks][it], Bl[jt], acc[it][jt], 0, 0, 0);
    }

    // ---- epilogue: sp[p] = sum_i q[i,p]*T[i,p] over this wave's 32 rows ----
    float sp[4];
    #pragma unroll
    for (int jt = 0; jt < 4; ++jt) sp[jt] = 0.f;
    #pragma unroll
    for (int jt = 0; jt < 4; ++jt) {
        #pragma unroll
        for (int it = 0; it < 2; ++it) {
            int irow = ibase + it * 16 + l4 * 4;
            const float* qp = qv + (size_t)irow * HW + jt * 16 + l15;
            #pragma unroll
            for (int r = 0; r < 4; ++r)
                sp[jt] = fmaf(qp[(size_t)r * HW], acc[it][jt][r], sp[jt]);
        }
        sp[jt] += __shfl_xor(sp[jt], 16, 64);
        sp[jt] += __shfl_xor(sp[jt], 32, 64);
    }

    // all waves past the loop -> safe to reuse Kh_s as reduction scratch
    __syncthreads();
    float* s_red = (float*)Kh_s;        // [8][PT]
    if (lane < 16) {
        #pragma unroll
        for (int jt = 0; jt < 4; ++jt)
            s_red[w * PT + jt * 16 + lane] = sp[jt];
    }
    __syncthreads();
    if (tid < PT) {
        float s = 0.f;
        #pragma unroll
        for (int ww = 0; ww < 8; ++ww) s += s_red[ww * PT + tid];
        score[v * HW + gp0 + tid] = s;
    }
}

// ---------------------------------------------------------------------------
// K4: split Wv into bf16 hi/lo (reuses the Mh/Ml workspace).
// ---------------------------------------------------------------------------
__global__ void wsplit_kernel(const float* __restrict__ Wv,
                              unsigned short* __restrict__ Wvh,
                              unsigned short* __restrict__ Wvl) {
    const int i = blockIdx.x;
    const int j = threadIdx.x;
    unsigned short h, l;
    split2(Wv[i * C_DIM + j], h, l);
    Wvh[i * C_DIM + j] = h;
    Wvl[i * C_DIM + j] = l;
}

// ---------------------------------------------------------------------------
// K5 (unchanged): out = Wv @ vbar with inline softmax.  ~21 us vs ~19 floor.
// ---------------------------------------------------------------------------
__global__ __launch_bounds__(512, 2) void out_gemm_kernel(
        const float* __restrict__ vin,
        const unsigned short* __restrict__ Wvh,
        const unsigned short* __restrict__ Wvl,
        const float* __restrict__ score,
        float* __restrict__ out) {
    const int tid  = threadIdx.x;
    const int lane = tid & 63;
    const int w    = tid >> 6;          // 0..7
    const int gp0  = blockIdx.x * PT;
    const int l15  = lane & 15;
    const int l4   = lane >> 4;
    const int jg   = w;                 // staging channel group (4 ch)

    __shared__ __align__(16) unsigned short Xh_s[2][KT];
    __shared__ __align__(16) unsigned short Xl_s[2][KT];

    float wr[V_DIM];
    {
        float s[V_DIM];
        float mx = -1e30f;
        #pragma unroll
        for (int vv = 0; vv < V_DIM; ++vv) {
            s[vv] = score[vv * HW + gp0 + lane];
            mx = fmaxf(mx, s[vv]);
        }
        float sum = 0.f;
        #pragma unroll
        for (int vv = 0; vv < V_DIM; ++vv) {
            s[vv] = __expf(s[vv] - mx);
            sum += s[vv];
        }
        float inv = 1.0f / sum;
        #pragma unroll
        for (int vv = 0; vv < V_DIM; ++vv) wr[vv] = s[vv] * inv;
    }

    const float* vbase = vin + gp0 + lane;
    const int obase = w * 32;

    f32x4 acc[2][4];
    #pragma unroll
    for (int a = 0; a < 2; ++a)
        #pragma unroll
        for (int b = 0; b < 4; ++b)
            acc[a][b] = (f32x4){0.f, 0.f, 0.f, 0.f};

    float vx[2][4][V_DIM];
    bf16x8 Ah[2][2], Al[2][2];

    {
        float x0[4][V_DIM];
        #pragma unroll
        for (int vv = 0; vv < V_DIM; ++vv)
            #pragma unroll
            for (int e = 0; e < 4; ++e)
                x0[e][vv] = vbase[(size_t)(vv * C_DIM + jg * 4 + e) * HW];
        unsigned short h[4], l[4];
        #pragma unroll
        for (int e = 0; e < 4; ++e) {
            float s = 0.f;
            #pragma unroll
            for (int vv = 0; vv < V_DIM; ++vv) s = fmaf(wr[vv], x0[e][vv], s);
            split2(s, h[e], l[e]);
        }
        uint2 H, L;
        H.x = (unsigned)h[0] | ((unsigned)h[1] << 16);
        H.y = (unsigned)h[2] | ((unsigned)h[3] << 16);
        L.x = (unsigned)l[0] | ((unsigned)l[1] << 16);
        L.y = (unsigned)l[2] | ((unsigned)l[3] << 16);
        *(uint2*)&Xh_s[0][lane * KROW + jg * 4] = H;
        *(uint2*)&Xl_s[0][lane * KROW + jg * 4] = L;

        #pragma unroll
        for (int vv = 0; vv < V_DIM; ++vv)
            #pragma unroll
            for (int e = 0; e < 4; ++e)
                vx[1][e][vv] = vbase[(size_t)(vv * C_DIM + BK + jg * 4 + e) * HW];

        #pragma unroll
        for (int it = 0; it < 2; ++it) {
            int row = obase + it * 16 + l15;
            Ah[0][it] = *(const bf16x8*)(Wvh + (size_t)row * C_DIM + l4 * 8);
            Al[0][it] = *(const bf16x8*)(Wvl + (size_t)row * C_DIM + l4 * 8);
        }
    }
    __syncthreads();

    #pragma unroll
    for (int ks = 0; ks < 8; ++ks) {
        const int cur = ks & 1;

        if (ks < 7) {
            #pragma unroll
            for (int it = 0; it < 2; ++it) {
                int row = obase + it * 16 + l15;
                Ah[cur ^ 1][it] = *(const bf16x8*)(Wvh + (size_t)row * C_DIM +
                                                   (ks + 1) * BK + l4 * 8);
                Al[cur ^ 1][it] = *(const bf16x8*)(Wvl + (size_t)row * C_DIM +
                                                   (ks + 1) * BK + l4 * 8);
            }
        }
        if (ks < 6) {
            #pragma unroll
            for (int vv = 0; vv < V_DIM; ++vv)
                #pragma unroll
                for (int e = 0; e < 4; ++e)
                    vx[cur][e][vv] = vbase[(size_t)(vv * C_DIM + (ks + 2) * BK +
                                                    jg * 4 + e) * HW];
        }

        bf16x8 Bh[4], Bl[4];
        #pragma unroll
        for (int jt = 0; jt < 4; ++jt) {
            int bp = jt * 16 + l15;
            Bh[jt] = *(const bf16x8*)&Xh_s[cur][bp * KROW + l4 * 8];
            Bl[jt] = *(const bf16x8*)&Xl_s[cur][bp * KROW + l4 * 8];
        }
        #pragma unroll
        for (int it = 0; it < 2; ++it)
            #pragma unroll
            for (int jt = 0; jt < 4; ++jt)
                acc[it][jt] = __builtin_amdgcn_mfma_f32_16x16x32_bf16(
                                  Ah[cur][it], Bh[jt], acc[it][jt], 0, 0, 0);
        #pragma unroll
        for (int it = 0; it < 2; ++it)
            #pragma unroll
            for (int jt = 0; jt < 4; ++jt)
                acc[it][jt] = __builtin_amdgcn_mfma_f32_16x16x32_bf16(
                                  Ah[cur][it], Bl[jt], acc[it][jt], 0, 0, 0);
        #pragma unroll
        for (int it = 0; it < 2; ++it)
            #pragma unroll
            for (int jt = 0; jt < 4; ++jt)
                acc[it][jt] = __builtin_amdgcn_mfma_f32_16x16x32_bf16(
                                  Al[cur][it], Bh[jt], acc[it][jt], 0, 0, 0);

        if (ks < 7) {
            unsigned short h[4], l[4];
            #pragma unroll
            for (int e = 0; e < 4; ++e) {
                float s = 0.f;
                #pragma unroll
                for (int vv = 0; vv < V_DIM; ++vv)
                    s = fmaf(wr[vv], vx[cur ^ 1][e][vv], s);
                split2(s, h[e], l[e]);
            }
            uint2 H, L;
            H.x = (unsigned)h[0] | ((unsigned)h[1] << 16);
            H.y = (unsigned)h[2] | ((unsigned)h[3] << 16);
            L.x = (unsigned)l[0] | ((unsigned)l[1] << 16);
            L.y = (unsigned)l[2] | ((unsigned)l[3] << 16);
            *(uint2*)&Xh_s[cur ^ 1][lane * KROW + jg * 4] = H;
            *(uint2*)&Xl_s[cur ^ 1][lane * KROW + jg * 4] = L;
        }
        __syncthreads();
    }

    #pragma unroll
    for (int it = 0; it < 2; ++it)
        #pragma unroll
        for (int jt = 0; jt < 4; ++jt)
            #pragma unroll
            for (int r = 0; r < 4; ++r) {
                int o = obase + it * 16 + l4 * 4 + r;
                out[(size_t)o * HW + gp0 + jt * 16 + l15] = acc[it][jt][r];
            }
}

// ---------------------------------------------------------------------------
extern "C" void kernel_launch(void* const* d_in, const int* in_sizes, int n_in,
                              void* d_out, int out_size, void* d_ws, size_t ws_size,
                              hipStream_t stream) {
    const float* q  = (const float*)d_in[0];
    const float* k  = (const float*)d_in[1];
    const float* v  = (const float*)d_in[2];
    const float* Wq = (const float*)d_in[3];
    const float* Wk = (const float*)d_in[4];
    const float* Wv = (const float*)d_in[5];
    float* out = (float*)d_out;

    unsigned short* Mh = (unsigned short*)d_ws;          // 128 KB (later: Wvh)
    unsigned short* Ml = Mh + C_DIM * C_DIM;             // 128 KB (later: Wvl)
    float* score = (float*)(Ml + C_DIM * C_DIM);         // 384 KB

    compute_M_kernel<<<C_DIM, C_DIM, 0, stream>>>(Wq, Wk, Mh, Ml);
    score_kernel<<<V_DIM * 256, 512, 0, stream>>>(q, k, Mh, Ml, score);
    wsplit_kernel<<<C_DIM, C_DIM, 0, stream>>>(Wv, Mh, Ml);
    out_gemm_kernel<<<HW / PT, 512, 0, stream>>>(v, Mh, Ml, score, out);
}

// Round 13
// 109.563 us; speedup vs baseline: 1.2512x; 1.2512x over previous
//
#include <hip/hip_runtime.h>
#include <math.h>

#define HW 16384
#define C_DIM 256
#define V_DIM 6
#define PT 64
#define BK 32
#define KROW 40            // ushorts per pixel-row (80 B): b128 ops at bank floor
#define KT (PT * KROW)     // ushorts per K-tile in LDS

typedef short bf16x8 __attribute__((ext_vector_type(8)));
typedef float f32x4 __attribute__((ext_vector_type(4)));

// fp32 -> bf16 hi/lo split (truncation). |x - (hi+lo)| <= 2^-16 |x|.
__device__ __forceinline__ void split2(float x, unsigned short& h,
                                       unsigned short& l) {
    unsigned u = __float_as_uint(x);
    h = (unsigned short)(u >> 16);
    float xl = x - __uint_as_float(u & 0xFFFF0000u);
    l = (unsigned short)(__float_as_uint(xl) >> 16);
}

// ---------------------------------------------------------------------------
// K1: M = Wq^T @ Wk, stored as bf16 hi/lo.
// ---------------------------------------------------------------------------
__global__ void compute_M_kernel(const float* __restrict__ Wq,
                                 const float* __restrict__ Wk,
                                 unsigned short* __restrict__ Mh,
                                 unsigned short* __restrict__ Ml) {
    const int i = blockIdx.x;
    const int j = threadIdx.x;
    float a0 = 0.f, a1 = 0.f, a2 = 0.f, a3 = 0.f;
    #pragma unroll 4
    for (int o = 0; o < C_DIM; o += 4) {
        a0 = fmaf(Wq[(o + 0) * C_DIM + i], Wk[(o + 0) * C_DIM + j], a0);
        a1 = fmaf(Wq[(o + 1) * C_DIM + i], Wk[(o + 1) * C_DIM + j], a1);
        a2 = fmaf(Wq[(o + 2) * C_DIM + i], Wk[(o + 2) * C_DIM + j], a2);
        a3 = fmaf(Wq[(o + 3) * C_DIM + i], Wk[(o + 3) * C_DIM + j], a3);
    }
    float acc = (a0 + a1) + (a2 + a3);
    unsigned short h, l;
    split2(acc, h, l);
    Mh[i * C_DIM + j] = h;
    Ml[i * C_DIM + j] = l;
}

// ---------------------------------------------------------------------------
// K2 v13: 256 blocks (ONE PER CU, like out_gemm), each handling ALL 6 VIEWS
// of one 64-pixel tile, view-pipelined.
// Why: every 1536-block variant (r2..r12) ran ~100 us at exactly ~1 TB/s
// effective HBM -- by Little's law that is ~1.5 KB in flight per CU, i.e.
// load-burst/drain/compute alternation across 6 serial block generations.
// out_gemm (256 blocks, one generation, continuously pipelined) moves the
// same bytes at ~5x the effective BW. This kernel copies that shape:
//   * k(v) staged as a full 8-tile LDS image (80 KB, r10 layout);
//   * kreg raw floats for view v+1 issued right after view v's image is
//     built -> in flight across view v's ENTIRE compute (~2-4 us >> 900cy);
//   * q(v) issued BEFORE k(v+1) (older in vmcnt order, so the epilogue's
//     q-wait leaves the k loads outstanding);
//   * ks-loop: A depth-1 from L2 (same addresses every view -> hot), B from
//     LDS, 24 MFMAs, no barriers inside;
//   * M L2 traffic drops 6x vs r11 (per-block A-frags reused by all views).
// ---------------------------------------------------------------------------
__global__ __launch_bounds__(512, 2) void score_kernel(
        const float* __restrict__ q, const float* __restrict__ k,
        const unsigned short* __restrict__ Mh,
        const unsigned short* __restrict__ Ml,
        float* __restrict__ score) {
    const int tid  = threadIdx.x;
    const int lane = tid & 63;          // staging pixel
    const int w    = tid >> 6;          // wave 0..7; staging ch-group (4 ch)
    const int gp0  = blockIdx.x * PT;
    const int l15  = lane & 15;
    const int l4   = lane >> 4;

    __shared__ __align__(16) unsigned short Kh_s[8 * KT];   // 40 KB
    __shared__ __align__(16) unsigned short Kl_s[8 * KT];   // 40 KB

    const int ibase = w * 32;

    // ---- prologue: issue k(view 0) loads ----
    float kreg[8][4];
    {
        const float* kv = k + gp0;      // view 0
        #pragma unroll
        for (int t = 0; t < 8; ++t) {
            const float* kp = kv + (size_t)(t * BK + w * 4) * HW + lane;
            #pragma unroll
            for (int e = 0; e < 4; ++e) kreg[t][e] = kp[(size_t)e * HW];
        }
    }

    for (int v = 0; v < V_DIM; ++v) {
        const float* qv = q + (size_t)v * C_DIM * HW + gp0;

        // (d) protect s_red readers of the previous view from our writes
        if (v > 0) __syncthreads();

        // ---- split current view's kreg -> LDS image ----
        #pragma unroll
        for (int t = 0; t < 8; ++t) {
            unsigned short h[4], l[4];
            #pragma unroll
            for (int e = 0; e < 4; ++e) split2(kreg[t][e], h[e], l[e]);
            uint2 H, L;
            H.x = (unsigned)h[0] | ((unsigned)h[1] << 16);
            H.y = (unsigned)h[2] | ((unsigned)h[3] << 16);
            L.x = (unsigned)l[0] | ((unsigned)l[1] << 16);
            L.y = (unsigned)l[2] | ((unsigned)l[3] << 16);
            *(uint2*)&Kh_s[t * KT + lane * KROW + w * 4] = H;
            *(uint2*)&Kl_s[t * KT + lane * KROW + w * 4] = L;
        }
        __syncthreads();   // (a) image ready

        // ---- issue q(v) (older) then k(v+1) (newer) ----
        float qx[32];
        #pragma unroll
        for (int jt = 0; jt < 4; ++jt)
            #pragma unroll
            for (int it = 0; it < 2; ++it) {
                int irow = ibase + it * 16 + l4 * 4;
                const float* qp = qv + (size_t)irow * HW + jt * 16 + l15;
                #pragma unroll
                for (int r = 0; r < 4; ++r)
                    qx[jt * 8 + it * 4 + r] = qp[(size_t)r * HW];
            }
        if (v < V_DIM - 1) {
            const float* kv = k + (size_t)(v + 1) * C_DIM * HW + gp0;
            #pragma unroll
            for (int t = 0; t < 8; ++t) {
                const float* kp = kv + (size_t)(t * BK + w * 4) * HW + lane;
                #pragma unroll
                for (int e = 0; e < 4; ++e) kreg[t][e] = kp[(size_t)e * HW];
            }
        }

        // ---- ks-loop: A depth-1 from L2, B from LDS, no barriers ----
        f32x4 acc[2][4];
        #pragma unroll
        for (int a = 0; a < 2; ++a)
            #pragma unroll
            for (int b = 0; b < 4; ++b)
                acc[a][b] = (f32x4){0.f, 0.f, 0.f, 0.f};

        bf16x8 Ah[2][2], Al[2][2];
        #pragma unroll
        for (int it = 0; it < 2; ++it) {
            int row = ibase + it * 16 + l15;
            Ah[0][it] = *(const bf16x8*)(Mh + (size_t)row * C_DIM + l4 * 8);
            Al[0][it] = *(const bf16x8*)(Ml + (size_t)row * C_DIM + l4 * 8);
        }

        #pragma unroll
        for (int ks = 0; ks < 8; ++ks) {
            const int cur = ks & 1;
            if (ks < 7) {
                #pragma unroll
                for (int it = 0; it < 2; ++it) {
                    int row = ibase + it * 16 + l15;
                    Ah[cur ^ 1][it] = *(const bf16x8*)(Mh + (size_t)row * C_DIM +
                                                       (ks + 1) * BK + l4 * 8);
                    Al[cur ^ 1][it] = *(const bf16x8*)(Ml + (size_t)row * C_DIM +
                                                       (ks + 1) * BK + l4 * 8);
                }
            }
            bf16x8 Bh[4];
            #pragma unroll
            for (int jt = 0; jt < 4; ++jt) {
                int bp = jt * 16 + l15;
                Bh[jt] = *(const bf16x8*)&Kh_s[ks * KT + bp * KROW + l4 * 8];
            }
            #pragma unroll
            for (int it = 0; it < 2; ++it)
                #pragma unroll
                for (int jt = 0; jt < 4; ++jt)
                    acc[it][jt] = __builtin_amdgcn_mfma_f32_16x16x32_bf16(
                                      Ah[cur][it], Bh[jt], acc[it][jt], 0, 0, 0);
            #pragma unroll
            for (int it = 0; it < 2; ++it)
                #pragma unroll
                for (int jt = 0; jt < 4; ++jt)
                    acc[it][jt] = __builtin_amdgcn_mfma_f32_16x16x32_bf16(
                                      Al[cur][it], Bh[jt], acc[it][jt], 0, 0, 0);
            bf16x8 Bl[4];
            #pragma unroll
            for (int jt = 0; jt < 4; ++jt) {
                int bp = jt * 16 + l15;
                Bl[jt] = *(const bf16x8*)&Kl_s[ks * KT + bp * KROW + l4 * 8];
            }
            #pragma unroll
            for (int it = 0; it < 2; ++it)
                #pragma unroll
                for (int jt = 0; jt < 4; ++jt)
                    acc[it][jt] = __builtin_amdgcn_mfma_f32_16x16x32_bf16(
                                      Ah[cur][it], Bl[jt], acc[it][jt], 0, 0, 0);
        }

        // ---- epilogue: sp = q . T (registers only) ----
        float sp[4];
        #pragma unroll
        for (int jt = 0; jt < 4; ++jt) sp[jt] = 0.f;
        #pragma unroll
        for (int jt = 0; jt < 4; ++jt) {
            #pragma unroll
            for (int it = 0; it < 2; ++it)
                #pragma unroll
                for (int r = 0; r < 4; ++r)
                    sp[jt] = fmaf(qx[jt * 8 + it * 4 + r],
                                  acc[it][jt][r], sp[jt]);
            sp[jt] += __shfl_xor(sp[jt], 16, 64);
            sp[jt] += __shfl_xor(sp[jt], 32, 64);
        }

        __syncthreads();   // (b) all B-reads done -> Kh_s reusable as scratch
        float* s_red = (float*)Kh_s;    // [8][PT]
        if (lane < 16) {
            #pragma unroll
            for (int jt = 0; jt < 4; ++jt)
                s_red[w * PT + jt * 16 + lane] = sp[jt];
        }
        __syncthreads();   // (c)
        if (tid < PT) {
            float s = 0.f;
            #pragma unroll
            for (int ww = 0; ww < 8; ++ww) s += s_red[ww * PT + tid];
            score[v * HW + gp0 + tid] = s;
        }
        // (d) at loop top protects s_red readers from next view's split
    }
}

// ---------------------------------------------------------------------------
// K4: split Wv into bf16 hi/lo (reuses the Mh/Ml workspace).
// ---------------------------------------------------------------------------
__global__ void wsplit_kernel(const float* __restrict__ Wv,
                              unsigned short* __restrict__ Wvh,
                              unsigned short* __restrict__ Wvl) {
    const int i = blockIdx.x;
    const int j = threadIdx.x;
    unsigned short h, l;
    split2(Wv[i * C_DIM + j], h, l);
    Wvh[i * C_DIM + j] = h;
    Wvl[i * C_DIM + j] = l;
}

// ---------------------------------------------------------------------------
// K5 (unchanged): out = Wv @ vbar with inline softmax.  ~21 us vs ~19 floor.
// ---------------------------------------------------------------------------
__global__ __launch_bounds__(512, 2) void out_gemm_kernel(
        const float* __restrict__ vin,
        const unsigned short* __restrict__ Wvh,
        const unsigned short* __restrict__ Wvl,
        const float* __restrict__ score,
        float* __restrict__ out) {
    const int tid  = threadIdx.x;
    const int lane = tid & 63;
    const int w    = tid >> 6;          // 0..7
    const int gp0  = blockIdx.x * PT;
    const int l15  = lane & 15;
    const int l4   = lane >> 4;
    const int jg   = w;                 // staging channel group (4 ch)

    __shared__ __align__(16) unsigned short Xh_s[2][KT];
    __shared__ __align__(16) unsigned short Xl_s[2][KT];

    float wr[V_DIM];
    {
        float s[V_DIM];
        float mx = -1e30f;
        #pragma unroll
        for (int vv = 0; vv < V_DIM; ++vv) {
            s[vv] = score[vv * HW + gp0 + lane];
            mx = fmaxf(mx, s[vv]);
        }
        float sum = 0.f;
        #pragma unroll
        for (int vv = 0; vv < V_DIM; ++vv) {
            s[vv] = __expf(s[vv] - mx);
            sum += s[vv];
        }
        float inv = 1.0f / sum;
        #pragma unroll
        for (int vv = 0; vv < V_DIM; ++vv) wr[vv] = s[vv] * inv;
    }

    const float* vbase = vin + gp0 + lane;
    const int obase = w * 32;

    f32x4 acc[2][4];
    #pragma unroll
    for (int a = 0; a < 2; ++a)
        #pragma unroll
        for (int b = 0; b < 4; ++b)
            acc[a][b] = (f32x4){0.f, 0.f, 0.f, 0.f};

    float vx[2][4][V_DIM];
    bf16x8 Ah[2][2], Al[2][2];

    {
        float x0[4][V_DIM];
        #pragma unroll
        for (int vv = 0; vv < V_DIM; ++vv)
            #pragma unroll
            for (int e = 0; e < 4; ++e)
                x0[e][vv] = vbase[(size_t)(vv * C_DIM + jg * 4 + e) * HW];
        unsigned short h[4], l[4];
        #pragma unroll
        for (int e = 0; e < 4; ++e) {
            float s = 0.f;
            #pragma unroll
            for (int vv = 0; vv < V_DIM; ++vv) s = fmaf(wr[vv], x0[e][vv], s);
            split2(s, h[e], l[e]);
        }
        uint2 H, L;
        H.x = (unsigned)h[0] | ((unsigned)h[1] << 16);
        H.y = (unsigned)h[2] | ((unsigned)h[3] << 16);
        L.x = (unsigned)l[0] | ((unsigned)l[1] << 16);
        L.y = (unsigned)l[2] | ((unsigned)l[3] << 16);
        *(uint2*)&Xh_s[0][lane * KROW + jg * 4] = H;
        *(uint2*)&Xl_s[0][lane * KROW + jg * 4] = L;

        #pragma unroll
        for (int vv = 0; vv < V_DIM; ++vv)
            #pragma unroll
            for (int e = 0; e < 4; ++e)
                vx[1][e][vv] = vbase[(size_t)(vv * C_DIM + BK + jg * 4 + e) * HW];

        #pragma unroll
        for (int it = 0; it < 2; ++it) {
            int row = obase + it * 16 + l15;
            Ah[0][it] = *(const bf16x8*)(Wvh + (size_t)row * C_DIM + l4 * 8);
            Al[0][it] = *(const bf16x8*)(Wvl + (size_t)row * C_DIM + l4 * 8);
        }
    }
    __syncthreads();

    #pragma unroll
    for (int ks = 0; ks < 8; ++ks) {
        const int cur = ks & 1;

        if (ks < 7) {
            #pragma unroll
            for (int it = 0; it < 2; ++it) {
                int row = obase + it * 16 + l15;
                Ah[cur ^ 1][it] = *(const bf16x8*)(Wvh + (size_t)row * C_DIM +
                                                   (ks + 1) * BK + l4 * 8);
                Al[cur ^ 1][it] = *(const bf16x8*)(Wvl + (size_t)row * C_DIM +
                                                   (ks + 1) * BK + l4 * 8);
            }
        }
        if (ks < 6) {
            #pragma unroll
            for (int vv = 0; vv < V_DIM; ++vv)
                #pragma unroll
                for (int e = 0; e < 4; ++e)
                    vx[cur][e][vv] = vbase[(size_t)(vv * C_DIM + (ks + 2) * BK +
                                                    jg * 4 + e) * HW];
        }

        bf16x8 Bh[4], Bl[4];
        #pragma unroll
        for (int jt = 0; jt < 4; ++jt) {
            int bp = jt * 16 + l15;
            Bh[jt] = *(const bf16x8*)&Xh_s[cur][bp * KROW + l4 * 8];
            Bl[jt] = *(const bf16x8*)&Xl_s[cur][bp * KROW + l4 * 8];
        }
        #pragma unroll
        for (int it = 0; it < 2; ++it)
            #pragma unroll
            for (int jt = 0; jt < 4; ++jt)
                acc[it][jt] = __builtin_amdgcn_mfma_f32_16x16x32_bf16(
                                  Ah[cur][it], Bh[jt], acc[it][jt], 0, 0, 0);
        #pragma unroll
        for (int it = 0; it < 2; ++it)
            #pragma unroll
            for (int jt = 0; jt < 4; ++jt)
                acc[it][jt] = __builtin_amdgcn_mfma_f32_16x16x32_bf16(
                                  Ah[cur][it], Bl[jt], acc[it][jt], 0, 0, 0);
        #pragma unroll
        for (int it = 0; it < 2; ++it)
            #pragma unroll
            for (int jt = 0; jt < 4; ++jt)
                acc[it][jt] = __builtin_amdgcn_mfma_f32_16x16x32_bf16(
                                  Al[cur][it], Bh[jt], acc[it][jt], 0, 0, 0);

        if (ks < 7) {
            unsigned short h[4], l[4];
            #pragma unroll
            for (int e = 0; e < 4; ++e) {
                float s = 0.f;
                #pragma unroll
                for (int vv = 0; vv < V_DIM; ++vv)
                    s = fmaf(wr[vv], vx[cur ^ 1][e][vv], s);
                split2(s, h[e], l[e]);
            }
            uint2 H, L;
            H.x = (unsigned)h[0] | ((unsigned)h[1] << 16);
            H.y = (unsigned)h[2] | ((unsigned)h[3] << 16);
            L.x = (unsigned)l[0] | ((unsigned)l[1] << 16);
            L.y = (unsigned)l[2] | ((unsigned)l[3] << 16);
            *(uint2*)&Xh_s[cur ^ 1][lane * KROW + jg * 4] = H;
            *(uint2*)&Xl_s[cur ^ 1][lane * KROW + jg * 4] = L;
        }
        __syncthreads();
    }

    #pragma unroll
    for (int it = 0; it < 2; ++it)
        #pragma unroll
        for (int jt = 0; jt < 4; ++jt)
            #pragma unroll
            for (int r = 0; r < 4; ++r) {
                int o = obase + it * 16 + l4 * 4 + r;
                out[(size_t)o * HW + gp0 + jt * 16 + l15] = acc[it][jt][r];
            }
}

// ---------------------------------------------------------------------------
extern "C" void kernel_launch(void* const* d_in, const int* in_sizes, int n_in,
                              void* d_out, int out_size, void* d_ws, size_t ws_size,
                              hipStream_t stream) {
    const float* q  = (const float*)d_in[0];
    const float* k  = (const float*)d_in[1];
    const float* v  = (const float*)d_in[2];
    const float* Wq = (const float*)d_in[3];
    const float* Wk = (const float*)d_in[4];
    const float* Wv = (const float*)d_in[5];
    float* out = (float*)d_out;

    unsigned short* Mh = (unsigned short*)d_ws;          // 128 KB (later: Wvh)
    unsigned short* Ml = Mh + C_DIM * C_DIM;             // 128 KB (later: Wvl)
    float* score = (float*)(Ml + C_DIM * C_DIM);         // 384 KB

    compute_M_kernel<<<C_DIM, C_DIM, 0, stream>>>(Wq, Wk, Mh, Ml);
    score_kernel<<<HW / PT, 512, 0, stream>>>(q, k, Mh, Ml, score);
    wsplit_kernel<<<C_DIM, C_DIM, 0, stream>>>(Wv, Mh, Ml);
    out_gemm_kernel<<<HW / PT, 512, 0, stream>>>(v, Mh, Ml, score, out);
}